// Round 15
// baseline (580.931 us; speedup 1.0000x reference)
//
#include <hip/hip_runtime.h>
#include <cstdint>
#include <cstddef>

typedef unsigned short u16;
typedef unsigned int u32;
typedef short s16x8 __attribute__((ext_vector_type(8)));   // 8 bf16 in 4 VGPRs
typedef float f32x4 __attribute__((ext_vector_type(4)));

// Problem constants: B=4,S=2048 -> T=8192 tokens, D=1024, H=4096, DO=1024, E=8, K=2
#define T_TOK 8192
#define D_IN  1024
#define H_DIM 4096
#define DO_DIM 1024

__device__ __forceinline__ u16 f2bf(float f) {  // RNE f32 -> bf16
    u32 u = __float_as_uint(f);
    return (u16)((u + 0x7FFFu + ((u >> 16) & 1u)) >> 16);
}

__device__ __forceinline__ f32x4 mfma16(s16x8 a, s16x8 b, f32x4 c) {
    return __builtin_amdgcn_mfma_f32_16x16x32_bf16(a, b, c, 0, 0, 0);
}

// async 16B global->LDS (direct DMA, no VGPR round trip)
__device__ __forceinline__ void gload16(const void* g, void* l) {
    __builtin_amdgcn_global_load_lds(
        (const __attribute__((address_space(1))) void*)g,
        (__attribute__((address_space(3))) void*)l,
        16, 0, 0);
}

// ---------------- fused gate + weight-transpose ----------------
__global__ __launch_bounds__(256) void gate_transpose_kernel(
    const float* __restrict__ x, const float* __restrict__ gw,
    const float* __restrict__ gb, float* __restrict__ weights_out,
    float* __restrict__ topi_out, int* __restrict__ gcounts,   // padded: e*32
    int* __restrict__ tok_list, int* __restrict__ slot_of_tok,
    const float* __restrict__ w1, const float* __restrict__ w2,
    u16* __restrict__ w1t, u16* __restrict__ w2t,
    int chunk, int HC, int gate_blocks)
{
    __shared__ u16 tile[64][68];
    __shared__ int lcount[8];
    __shared__ int gbase[8];
    __shared__ short tinfo[16][4];

    const int bid = blockIdx.x;
    if (bid < gate_blocks) {
        const int wid = threadIdx.x >> 6;
        const int lane = threadIdx.x & 63;
        const int tbase = bid << 4;
        if (threadIdx.x < 8) lcount[threadIdx.x] = 0;
        __syncthreads();
        for (int j = 0; j < 4; ++j) {
            const int t = tbase + (wid << 2) + j;
            const float* xr = x + ((size_t)t << 10);
            float p[8];
#pragma unroll
            for (int e = 0; e < 8; ++e) p[e] = 0.f;
#pragma unroll
            for (int i = 0; i < 16; ++i) {
                int d = lane + i * 64;
                float xv = xr[d];
                const f32x4 g0 = *(const f32x4*)(gw + d * 8);
                const f32x4 g1 = *(const f32x4*)(gw + d * 8 + 4);
                p[0] += xv * g0[0]; p[1] += xv * g0[1]; p[2] += xv * g0[2]; p[3] += xv * g0[3];
                p[4] += xv * g1[0]; p[5] += xv * g1[1]; p[6] += xv * g1[2]; p[7] += xv * g1[3];
            }
#pragma unroll
            for (int off = 32; off >= 1; off >>= 1) {
#pragma unroll
                for (int e = 0; e < 8; ++e) p[e] += __shfl_xor(p[e], off, 64);
            }
            if (lane == 0) {
                float lg[8];
#pragma unroll
                for (int e = 0; e < 8; ++e) lg[e] = p[e] + gb[e];
                int i0 = 0;
                for (int e = 1; e < 8; ++e) if (lg[e] > lg[i0]) i0 = e;   // ties -> lowest idx
                int i1 = (i0 == 0) ? 1 : 0;
                for (int e = 0; e < 8; ++e) if (e != i0 && lg[e] > lg[i1]) i1 = e;
                float ex = expf(lg[i1] - lg[i0]);          // <= 1
                float p0 = 1.f / (1.f + ex);
                float p1 = ex / (1.f + ex);
#pragma unroll
                for (int e = 0; e < 8; ++e)
                    weights_out[t * 8 + e] = (e == i0) ? p0 : ((e == i1) ? p1 : 0.f);
                topi_out[t * 2 + 0] = (float)i0;
                topi_out[t * 2 + 1] = (float)i1;
                int idx = (wid << 2) + j;
                int r0 = atomicAdd(&lcount[i0], 1);
                int r1 = atomicAdd(&lcount[i1], 1);
                tinfo[idx][0] = (short)i0; tinfo[idx][1] = (short)r0;
                tinfo[idx][2] = (short)i1; tinfo[idx][3] = (short)r1;
            }
        }
        __syncthreads();
        if (threadIdx.x < 8)
            gbase[threadIdx.x] = atomicAdd(&gcounts[threadIdx.x * 32], lcount[threadIdx.x]);
        __syncthreads();
        if (threadIdx.x < 16) {
            int t = tbase + threadIdx.x;
            int i0 = tinfo[threadIdx.x][0], r0 = tinfo[threadIdx.x][1];
            int i1 = tinfo[threadIdx.x][2], r1 = tinfo[threadIdx.x][3];
            int pos0 = gbase[i0] + r0;
            int pos1 = gbase[i1] + r1;
            tok_list[(i0 << 13) + pos0] = t;
            slot_of_tok[t * 2 + 0] = (i0 << 13) | pos0;
            tok_list[(i1 << 13) + pos1] = t;
            slot_of_tok[t * 2 + 1] = (i1 << 13) | pos1;
        }
        return;
    }

    // ---------------- transpose+cvt ----------------
    const int tid = threadIdx.x;
    const int tiles_h = HC >> 6;
    const int per_e = 32 * tiles_h;
    const int ntile1 = 16 * tiles_h;
    const int b2 = bid - gate_blocks;
    const int e = b2 / per_e;
    const int b = b2 - e * per_e;
    const float* src; u16* dst;
    size_t sstride, dstride;
    int r0, c0;
    if (b < ntile1) {
        int tr = b / tiles_h, tc = b % tiles_h;
        r0 = tr * 64; c0 = tc * 64;
        src = w1 + (size_t)e * D_IN * H_DIM + (size_t)chunk * HC;
        sstride = H_DIM;
        dst = w1t + (size_t)e * HC * D_IN;
        dstride = D_IN;
    } else {
        int tb = b - ntile1;
        int tr = tb / 16, tc = tb % 16;
        r0 = tr * 64; c0 = tc * 64;
        src = w2 + ((size_t)e * H_DIM + (size_t)chunk * HC) * DO_DIM;
        sstride = DO_DIM;
        dst = w2t + (size_t)e * DO_DIM * HC;
        dstride = HC;
    }
#pragma unroll
    for (int i = 0; i < 4; ++i) {
        int flat = i * 1024 + tid * 4;
        int rr = flat >> 6, cc = flat & 63;
        float4 v = *(const float4*)(src + (size_t)(r0 + rr) * sstride + c0 + cc);
        ushort4 h4;
        h4.x = f2bf(v.x); h4.y = f2bf(v.y); h4.z = f2bf(v.z); h4.w = f2bf(v.w);
        *(ushort4*)&tile[rr][cc] = h4;
    }
    __syncthreads();
#pragma unroll
    for (int i = 0; i < 4; ++i) {
        int flat = i * 1024 + tid * 4;
        int rr = flat >> 6, cc = flat & 63;
        ushort4 o;
        o.x = tile[cc + 0][rr]; o.y = tile[cc + 1][rr];
        o.z = tile[cc + 2][rr]; o.w = tile[cc + 3][rr];
        *(ushort4*)(dst + (size_t)(c0 + rr) * dstride + r0 + cc) = o;
    }
}

__global__ void zero_counts_kernel(int* c) { c[threadIdx.x] = 0; }   // 256 ints (padded)

// scan padded gcounts -> compact counts, base[], usage, dense 128-row block table
__global__ void scan_kernel(const int* __restrict__ gcounts, int* __restrict__ counts,
                            int* __restrict__ base, float* __restrict__ usage_out,
                            int* __restrict__ rbt) {
    if (threadIdx.x == 0) {
        int acc = 0;
        for (int e = 0; e < 8; ++e) {
            int c = gcounts[e * 32];
            counts[e] = c;
            base[e] = acc;
            acc += c;
            usage_out[e] = (float)c;
        }
        int nrb = 0;
        for (int e = 0; e < 8; ++e) {
            int nb = (counts[e] + 127) >> 7;
            for (int rb = 0; rb < nb; ++rb) rbt[1 + nrb++] = (e << 16) | rb;
        }
        rbt[0] = nrb;   // <= 135
    }
}

// ---------------- gather: xg[slot][d] = bf16(x[tok][d]) ----------------
__global__ __launch_bounds__(256) void gather_kernel(
    const float* __restrict__ x, const int* __restrict__ slot_of_tok,
    const int* __restrict__ base, u16* __restrict__ xg)
{
    const int t = blockIdx.x;
    const int s = slot_of_tok[t * 2 + blockIdx.y];
    const int slot = base[s >> 13] + (s & 8191);
    const int d = threadIdx.x * 4;
    float4 v = *(const float4*)(x + ((size_t)t << 10) + d);
    ushort4 h;
    h.x = f2bf(v.x); h.y = f2bf(v.y); h.z = f2bf(v.z); h.w = f2bf(v.w);
    *(ushort4*)(xg + ((size_t)slot << 10) + d) = h;
}

// ====================== 128x256 BK=64 depth-3 pipelined MFMA GEMM cores ======================
// The r11/r12/r14-verified schedule (204us, 674TF, MfmaUtil 29, 0 bank conflicts), with
// pointer offsets parameterized (hoff for gemm1 H-range, kbase for gemm2 K-range) so the
// two GEMMs can be software-pipelined across an H-split: g1[0:H/2] ; {g1[H/2:H] || g2[K<H/2]}
// ; g2[K>=H/2]. Both kernels are latency-bound at 29% MfmaUtil — co-residency overlaps stalls.

__device__ __forceinline__ void stage6s(const char* const gA[2], const char* const gB[4],
                                        char* slab, int koff, int tid) {
    char* l = slab + __builtin_amdgcn_readfirstlane((tid >> 6) << 10);
#pragma unroll
    for (int i = 0; i < 2; ++i) gload16(gA[i] + koff, l + i * 8192);
#pragma unroll
    for (int i = 0; i < 4; ++i) gload16(gB[i] + koff, l + 16384 + i * 8192);
}

#define MFMA_BLOCK(S) do { \
    s16x8 la0[4], lb0[4], la1[4], lb1[4]; \
    _Pragma("unroll") \
    for (int m = 0; m < 4; ++m) la0[m] = *(const s16x8*)((S) + aoff0 + m * 2048); \
    _Pragma("unroll") \
    for (int n = 0; n < 4; ++n) lb0[n] = *(const s16x8*)((S) + boff0 + n * 2048); \
    _Pragma("unroll") \
    for (int m = 0; m < 4; ++m) la1[m] = *(const s16x8*)((S) + aoff1 + m * 2048); \
    _Pragma("unroll") \
    for (int n = 0; n < 4; ++n) lb1[n] = *(const s16x8*)((S) + boff1 + n * 2048); \
    __builtin_amdgcn_s_setprio(1); \
    _Pragma("unroll") \
    for (int m = 0; m < 4; ++m) \
        _Pragma("unroll") \
        for (int n = 0; n < 4; ++n) acc[m][n] = mfma16(la0[m], lb0[n], acc[m][n]); \
    _Pragma("unroll") \
    for (int m = 0; m < 4; ++m) \
        _Pragma("unroll") \
        for (int n = 0; n < 4; ++n) acc[m][n] = mfma16(la1[m], lb1[n], acc[m][n]); \
    __builtin_amdgcn_s_setprio(0); } while(0)

#define GEMM_CORE(NTV) \
    const int arow = (wm << 6) + (lane & 15); \
    const int brow = (wn << 6) + (lane & 15); \
    const int ko = (lane >> 4) << 4; \
    const int aoff0 = arow * 128 + (ko ^ ((arow & 7) << 4)); \
    const int aoff1 = arow * 128 + ((64 + ko) ^ ((arow & 7) << 4)); \
    const int boff0 = 16384 + brow * 128 + (ko ^ ((brow & 7) << 4)); \
    const int boff1 = 16384 + brow * 128 + ((64 + ko) ^ ((brow & 7) << 4)); \
    f32x4 acc[4][4]; \
    _Pragma("unroll") \
    for (int m = 0; m < 4; ++m) \
        _Pragma("unroll") \
        for (int n = 0; n < 4; ++n) acc[m][n] = f32x4{0.f, 0.f, 0.f, 0.f}; \
    stage6s(gA, gB, sm, 0, tid); \
    stage6s(gA, gB, sm + 49152, 128, tid); \
    int cs = 0; \
    _Pragma("unroll 1") \
    for (int t = 0; t < (NTV); ++t) { \
        if (t + 1 < (NTV)) asm volatile("s_waitcnt vmcnt(6)" ::: "memory"); \
        else               asm volatile("s_waitcnt vmcnt(0)" ::: "memory"); \
        __builtin_amdgcn_sched_barrier(0); \
        __builtin_amdgcn_s_barrier(); \
        __builtin_amdgcn_sched_barrier(0); \
        if (t + 2 < (NTV)) { \
            int ss = cs + 2; if (ss >= 3) ss -= 3; \
            stage6s(gA, gB, sm + ss * 49152, (t + 2) * 128, tid); \
        } \
        const char* S_ = sm + cs * 49152; \
        MFMA_BLOCK(S_); \
        cs = cs + 1; if (cs == 3) cs = 0; \
    }

// gemm1 body: hbuf[slot][hoff+col] = relu(xg[slot] @ w1t[e][hoff+col] + b1)
__device__ __forceinline__ void run_gemm1(
    char* sm, const u16* __restrict__ xg, const u16* __restrict__ w1t,
    const float* __restrict__ b1, u16* __restrict__ hbuf,
    const int* __restrict__ counts, const int* __restrict__ base,
    const int* __restrict__ rbt, int bx, int by, int hoff, int bo, int HC)
{
    const int nrb = rbt[0];
    if (by >= nrb) return;
    const int ent = rbt[1 + by];
    const int e = ent >> 16;
    const int row0 = (ent & 0xffff) << 7;
    const int n_e = counts[e];
    const int sbase = base[e];
    const int col0 = hoff + (bx << 8);
    const int tid = threadIdx.x;
    const int lane = tid & 63;
    const int wv = tid >> 6;
    const int wm = wv >> 2;
    const int wn = wv & 3;

    const int scb_ = ((tid & 7) << 4) ^ (((tid >> 3) & 7) << 4);
    const char* gA[2]; const char* gB[4];
#pragma unroll
    for (int i = 0; i < 2; ++i) {
        int slot = sbase + row0 + i * 64 + (tid >> 3);
        slot = slot < 16383 ? slot : 16383;
        gA[i] = (const char*)xg + ((size_t)slot << 11) + scb_;
    }
#pragma unroll
    for (int i = 0; i < 4; ++i) {
        int hrow = col0 + i * 64 + (tid >> 3);
        gB[i] = (const char*)w1t + (((size_t)e * HC + hrow) << 11) + scb_;
    }

    GEMM_CORE(16)

    const int crow = (wm << 6) + ((lane >> 4) << 2);
    const int ccol = (wn << 6) + (lane & 15);
    float bias_n[4];
#pragma unroll
    for (int n = 0; n < 4; ++n)
        bias_n[n] = b1[(e << 12) + bo + (bx << 8) + ccol + n * 16];
#pragma unroll
    for (int m = 0; m < 4; ++m) {
#pragma unroll
        for (int j = 0; j < 4; ++j) {
            int r = row0 + crow + m * 16 + j;
            if (r < n_e) {
                u16* dst = hbuf + (size_t)(sbase + r) * HC + col0;
#pragma unroll
                for (int n = 0; n < 4; ++n) {
                    float v = acc[m][n][j] + bias_n[n];
                    v = v > 0.f ? v : 0.f;
                    dst[ccol + n * 16] = f2bf(v);
                }
            }
        }
    }
}

// gemm2 body: eo[slot] (+)= hbuf[slot][kbase:kbase+64*NTV] @ w2t (+b2 iff kflag==0)
__device__ __forceinline__ void run_gemm2(
    char* sm, const u16* __restrict__ hbuf, const u16* __restrict__ w2t,
    const float* __restrict__ b2, float* __restrict__ eo,
    const int* __restrict__ counts, const int* __restrict__ base,
    const int* __restrict__ rbt, int bx, int by, int kbase, int NTV, int kflag, int HC)
{
    const int nrb = rbt[0];
    if (by >= nrb) return;
    const int ent = rbt[1 + by];
    const int e = ent >> 16;
    const int row0 = (ent & 0xffff) << 7;
    const int n_e = counts[e];
    const int sbase = base[e];
    const int col0 = bx << 8;
    const int tid = threadIdx.x;
    const int lane = tid & 63;
    const int wv = tid >> 6;
    const int wm = wv >> 2;
    const int wn = wv & 3;

    const int scb_ = ((tid & 7) << 4) ^ (((tid >> 3) & 7) << 4);
    const char* gA[2]; const char* gB[4];
#pragma unroll
    for (int i = 0; i < 2; ++i) {
        int slot = sbase + row0 + i * 64 + (tid >> 3);
        slot = slot < 16383 ? slot : 16383;
        gA[i] = (const char*)hbuf + (((size_t)slot * HC + kbase) << 1) + scb_;
    }
#pragma unroll
    for (int i = 0; i < 4; ++i) {
        int orow = col0 + i * 64 + (tid >> 3);
        gB[i] = (const char*)w2t + ((((size_t)(e << 10) + orow) * HC + kbase) << 1) + scb_;
    }

    GEMM_CORE(NTV)

    const int crow = (wm << 6) + ((lane >> 4) << 2);
    const int ccol = (wn << 6) + (lane & 15);
    float bias_n[4];
#pragma unroll
    for (int n = 0; n < 4; ++n)
        bias_n[n] = (kflag == 0) ? b2[(e << 10) + col0 + ccol + n * 16] : 0.f;
#pragma unroll
    for (int m = 0; m < 4; ++m) {
#pragma unroll
        for (int j = 0; j < 4; ++j) {
            int r = row0 + crow + m * 16 + j;
            if (r < n_e) {
                float* dst = eo + ((size_t)(sbase + r) << 10) + col0;
#pragma unroll
                for (int n = 0; n < 4; ++n) {
                    int c = ccol + n * 16;
                    float v = acc[m][n][j] + bias_n[n];
                    if (kflag) v += dst[c];
                    dst[c] = v;
                }
            }
        }
    }
}

__global__ __launch_bounds__(512) void gemm1_kernel(
    const u16* __restrict__ xg, const u16* __restrict__ w1t,
    const float* __restrict__ b1, u16* __restrict__ hbuf,
    const int* __restrict__ counts, const int* __restrict__ base,
    const int* __restrict__ rbt, int hoff, int bo, int HC)
{
    __shared__ char sm[147456];
    run_gemm1(sm, xg, w1t, b1, hbuf, counts, base, rbt,
              blockIdx.x, blockIdx.y, hoff, bo, HC);
}

__global__ __launch_bounds__(512) void gemm2_kernel(
    const u16* __restrict__ hbuf, const u16* __restrict__ w2t,
    const float* __restrict__ b2, float* __restrict__ eo,
    const int* __restrict__ counts, const int* __restrict__ base,
    const int* __restrict__ rbt, int kbase, int NTV, int kflag, int HC)
{
    __shared__ char sm[147456];
    run_gemm2(sm, hbuf, w2t, b2, eo, counts, base, rbt,
              blockIdx.x, blockIdx.y, kbase, NTV, kflag, HC);
}

// fused middle stage: bx<g1x -> gemm1 second H-half; else gemm2 first K-half.
// Blocks interleave on bx so both kinds co-schedule per CU (overlap latency stalls).
__global__ __launch_bounds__(512) void gemm_mid_kernel(
    const u16* __restrict__ xg, const u16* __restrict__ w1t,
    const float* __restrict__ b1, u16* __restrict__ hbuf,
    const u16* __restrict__ w2t, const float* __restrict__ b2,
    float* __restrict__ eo, const int* __restrict__ counts,
    const int* __restrict__ base, const int* __restrict__ rbt,
    int g1x, int hoff, int kNTV, int HC)
{
    __shared__ char sm[147456];
    if ((int)blockIdx.x < g1x)
        run_gemm1(sm, xg, w1t, b1, hbuf, counts, base, rbt,
                  blockIdx.x, blockIdx.y, hoff, hoff, HC);
    else
        run_gemm2(sm, hbuf, w2t, b2, eo, counts, base, rbt,
                  blockIdx.x - g1x, blockIdx.y, 0, kNTV, 0, HC);
}

// ---------------- combine: out[t] = w0*eo[s0] + w1*eo[s1] (deterministic) ----------------
__global__ __launch_bounds__(256) void combine_kernel(
    const float* __restrict__ eo, const float* __restrict__ weights,
    const int* __restrict__ slot_of_tok, const int* __restrict__ base,
    float* __restrict__ out)
{
    const int t = blockIdx.x;
    const int tid = threadIdx.x;
    int s0 = slot_of_tok[t * 2], s1 = slot_of_tok[t * 2 + 1];
    int e0 = s0 >> 13, e1 = s1 >> 13;
    int c0 = base[e0] + (s0 & 8191);
    int c1 = base[e1] + (s1 & 8191);
    float w0 = weights[t * 8 + e0];
    float w1 = weights[t * 8 + e1];
    int c = tid * 4;
    f32x4 a = *(const f32x4*)(eo + ((size_t)c0 << 10) + c);
    f32x4 b = *(const f32x4*)(eo + ((size_t)c1 << 10) + c);
    f32x4 r;
    r[0] = w0 * a[0] + w1 * b[0];
    r[1] = w0 * a[1] + w1 * b[1];
    r[2] = w0 * a[2] + w1 * b[2];
    r[3] = w0 * a[3] + w1 * b[3];
    *(f32x4*)(out + ((size_t)t << 10) + c) = r;
}

extern "C" void kernel_launch(void* const* d_in, const int* in_sizes, int n_in,
                              void* d_out, int out_size, void* d_ws, size_t ws_size,
                              hipStream_t stream)
{
    const float* x      = (const float*)d_in[0];
    const float* gate_w = (const float*)d_in[1];
    const float* gate_b = (const float*)d_in[2];
    const float* w1     = (const float*)d_in[3];
    const float* b1     = (const float*)d_in[4];
    const float* w2     = (const float*)d_in[5];
    const float* b2     = (const float*)d_in[6];

    float* out         = (float*)d_out;                      // [8192,1024]
    float* weights_out = out + (size_t)T_TOK * DO_DIM;       // [8192,8]
    float* usage_out   = weights_out + (size_t)T_TOK * 8;    // [8]
    float* topi_out    = usage_out + 8;                      // [8192,2]

    char* p = (char*)d_ws;
    int* gcounts = (int*)p;      p += 1024;                  // padded: e*32, 128B apart
    int* counts = (int*)p;       p += 256;
    int* base   = (int*)p;       p += 256;
    int* rbt    = (int*)p;       p += 1024;                  // 1 + <=135 entries
    int* tok_list = (int*)p;     p += (size_t)8 * 8192 * 4;
    int* slot_of_tok = (int*)p;  p += (size_t)8192 * 2 * 4;
    const size_t fixed = (size_t)(p - (char*)d_ws);

    // xg 32MiB + eo 64MiB fixed; per-HC: w1t+w2t+hbuf = 65536*HC bytes
    const size_t xg_bytes = (size_t)16384 * 1024 * 2;
    const size_t eo_bytes = (size_t)16384 * 1024 * 4;
    int HC;
    if      (ws_size >= fixed + xg_bytes + eo_bytes + (size_t)65536 * 4096) HC = 4096;
    else if (ws_size >= fixed + xg_bytes + eo_bytes + (size_t)65536 * 2048) HC = 2048;
    else if (ws_size >= fixed + xg_bytes + eo_bytes + (size_t)65536 * 1024) HC = 1024;
    else                                                                    HC = 512;

    u16* xg   = (u16*)p; p += xg_bytes;
    u16* w1t  = (u16*)p; p += (size_t)8 * HC * 1024 * 2;
    u16* w2t  = (u16*)p; p += (size_t)8 * 1024 * HC * 2;
    u16* hbuf = (u16*)p; p += (size_t)16384 * HC * 2;
    float* eo = (float*)p;

    const int tiles_h = HC / 64;
    const int per_e = 32 * tiles_h;
    const int trans_blocks = 8 * per_e;

    zero_counts_kernel<<<1, 256, 0, stream>>>(gcounts);
    gate_transpose_kernel<<<512 + trans_blocks, 256, 0, stream>>>(
        x, gate_w, gate_b, weights_out, topi_out, gcounts, tok_list, slot_of_tok,
        w1, w2, w1t, w2t, 0, HC, 512);
    scan_kernel<<<1, 64, 0, stream>>>(gcounts, counts, base, usage_out, rbt);
    gather_kernel<<<dim3(T_TOK, 2), 256, 0, stream>>>(x, slot_of_tok, base, xg);

    if (HC == 4096) {
        // H-split pipeline: g1[0:2048] ; {g1[2048:4096] || g2[K 0:2048]} ; g2[K 2048:4096]
        gemm1_kernel<<<dim3(8, 136), 512, 0, stream>>>(xg, w1t, b1, hbuf,
                                                       counts, base, rbt, 0, 0, HC);
        gemm_mid_kernel<<<dim3(12, 136), 512, 0, stream>>>(xg, w1t, b1, hbuf, w2t, b2, eo,
                                                           counts, base, rbt, 8, 2048, 32, HC);
        gemm2_kernel<<<dim3(4, 136), 512, 0, stream>>>(hbuf, w2t, b2, eo,
                                                       counts, base, rbt, 2048, 32, 1, HC);
    } else {
        const int NC = H_DIM / HC;
        for (int c = 0; c < NC; ++c) {
            if (c > 0)
                gate_transpose_kernel<<<trans_blocks, 256, 0, stream>>>(
                    x, gate_w, gate_b, weights_out, topi_out, gcounts, tok_list, slot_of_tok,
                    w1, w2, w1t, w2t, c, HC, 0);
            gemm1_kernel<<<dim3(HC / 256, 136, 1), 512, 0, stream>>>(xg, w1t, b1, hbuf,
                                                                     counts, base, rbt,
                                                                     0, c * HC, HC);
            gemm2_kernel<<<dim3(4, 136, 1), 512, 0, stream>>>(hbuf, w2t, b2, eo,
                                                              counts, base, rbt,
                                                              0, HC / 64, c > 0 ? 1 : 0, HC);
        }
    }
    combine_kernel<<<T_TOK, 256, 0, stream>>>(eo, weights_out, slot_of_tok, base, out);
}

// Round 16
// 511.483 us; speedup vs baseline: 1.1358x; 1.1358x over previous
//
#include <hip/hip_runtime.h>
#include <cstdint>
#include <cstddef>

typedef unsigned short u16;
typedef unsigned int u32;
typedef short s16x8 __attribute__((ext_vector_type(8)));   // 8 bf16 in 4 VGPRs
typedef float f32x4 __attribute__((ext_vector_type(4)));

// Problem constants: B=4,S=2048 -> T=8192 tokens, D=1024, H=4096, DO=1024, E=8, K=2
#define T_TOK 8192
#define D_IN  1024
#define H_DIM 4096
#define DO_DIM 1024
#define NRBP 136   // padded row-block groups (136 = 8*17, grid stays XCD-divisible)

__device__ __forceinline__ u16 f2bf(float f) {  // RNE f32 -> bf16
    u32 u = __float_as_uint(f);
    return (u16)((u + 0x7FFFu + ((u >> 16) & 1u)) >> 16);
}

__device__ __forceinline__ f32x4 mfma16(s16x8 a, s16x8 b, f32x4 c) {
    return __builtin_amdgcn_mfma_f32_16x16x32_bf16(a, b, c, 0, 0, 0);
}

// async 16B global->LDS (direct DMA, no VGPR round trip)
__device__ __forceinline__ void gload16(const void* g, void* l) {
    __builtin_amdgcn_global_load_lds(
        (const __attribute__((address_space(1))) void*)g,
        (__attribute__((address_space(3))) void*)l,
        16, 0, 0);
}

// XCD-cluster block mapping: flat id n -> (bx, by) such that all ncol column-blocks
// sharing one A-panel land on ONE XCD (dispatch n -> XCD n%8 round-robin assumption;
// affects locality only). c = min(ncol, 8); gp = ncol / c. Bijective for NRBP groups.
__device__ __forceinline__ void xcd_map(int n, int ncol, int* bx, int* by) {
    const int c  = ncol < 8 ? ncol : 8;
    const int gp = ncol / c;
    const int xcd = n & 7;
    const int k = n >> 3;
    const int sg = xcd + 8 * (k / c);
    *by = sg / gp;
    *bx = (sg % gp) * c + (k % c);
}

// ---------------- fused gate + weight-transpose ----------------
__global__ __launch_bounds__(256) void gate_transpose_kernel(
    const float* __restrict__ x, const float* __restrict__ gw,
    const float* __restrict__ gb, float* __restrict__ weights_out,
    float* __restrict__ topi_out, int* __restrict__ gcounts,   // padded: e*32
    int* __restrict__ tok_list, int* __restrict__ slot_of_tok,
    const float* __restrict__ w1, const float* __restrict__ w2,
    u16* __restrict__ w1t, u16* __restrict__ w2t,
    int chunk, int HC, int gate_blocks)
{
    __shared__ u16 tile[64][68];
    __shared__ int lcount[8];
    __shared__ int gbase[8];
    __shared__ short tinfo[16][4];

    const int bid = blockIdx.x;
    if (bid < gate_blocks) {
        const int wid = threadIdx.x >> 6;
        const int lane = threadIdx.x & 63;
        const int tbase = bid << 4;
        if (threadIdx.x < 8) lcount[threadIdx.x] = 0;
        __syncthreads();
        for (int j = 0; j < 4; ++j) {
            const int t = tbase + (wid << 2) + j;
            const float* xr = x + ((size_t)t << 10);
            float p[8];
#pragma unroll
            for (int e = 0; e < 8; ++e) p[e] = 0.f;
#pragma unroll
            for (int i = 0; i < 16; ++i) {
                int d = lane + i * 64;
                float xv = xr[d];
                const f32x4 g0 = *(const f32x4*)(gw + d * 8);
                const f32x4 g1 = *(const f32x4*)(gw + d * 8 + 4);
                p[0] += xv * g0[0]; p[1] += xv * g0[1]; p[2] += xv * g0[2]; p[3] += xv * g0[3];
                p[4] += xv * g1[0]; p[5] += xv * g1[1]; p[6] += xv * g1[2]; p[7] += xv * g1[3];
            }
#pragma unroll
            for (int off = 32; off >= 1; off >>= 1) {
#pragma unroll
                for (int e = 0; e < 8; ++e) p[e] += __shfl_xor(p[e], off, 64);
            }
            if (lane == 0) {
                float lg[8];
#pragma unroll
                for (int e = 0; e < 8; ++e) lg[e] = p[e] + gb[e];
                int i0 = 0;
                for (int e = 1; e < 8; ++e) if (lg[e] > lg[i0]) i0 = e;   // ties -> lowest idx
                int i1 = (i0 == 0) ? 1 : 0;
                for (int e = 0; e < 8; ++e) if (e != i0 && lg[e] > lg[i1]) i1 = e;
                float ex = expf(lg[i1] - lg[i0]);          // <= 1
                float p0 = 1.f / (1.f + ex);
                float p1 = ex / (1.f + ex);
#pragma unroll
                for (int e = 0; e < 8; ++e)
                    weights_out[t * 8 + e] = (e == i0) ? p0 : ((e == i1) ? p1 : 0.f);
                topi_out[t * 2 + 0] = (float)i0;
                topi_out[t * 2 + 1] = (float)i1;
                int idx = (wid << 2) + j;
                int r0 = atomicAdd(&lcount[i0], 1);
                int r1 = atomicAdd(&lcount[i1], 1);
                tinfo[idx][0] = (short)i0; tinfo[idx][1] = (short)r0;
                tinfo[idx][2] = (short)i1; tinfo[idx][3] = (short)r1;
            }
        }
        __syncthreads();
        if (threadIdx.x < 8)
            gbase[threadIdx.x] = atomicAdd(&gcounts[threadIdx.x * 32], lcount[threadIdx.x]);
        __syncthreads();
        if (threadIdx.x < 16) {
            int t = tbase + threadIdx.x;
            int i0 = tinfo[threadIdx.x][0], r0 = tinfo[threadIdx.x][1];
            int i1 = tinfo[threadIdx.x][2], r1 = tinfo[threadIdx.x][3];
            int pos0 = gbase[i0] + r0;
            int pos1 = gbase[i1] + r1;
            tok_list[(i0 << 13) + pos0] = t;
            slot_of_tok[t * 2 + 0] = (i0 << 13) | pos0;
            tok_list[(i1 << 13) + pos1] = t;
            slot_of_tok[t * 2 + 1] = (i1 << 13) | pos1;
        }
        return;
    }

    // ---------------- transpose+cvt ----------------
    const int tid = threadIdx.x;
    const int tiles_h = HC >> 6;
    const int per_e = 32 * tiles_h;
    const int ntile1 = 16 * tiles_h;
    const int b2 = bid - gate_blocks;
    const int e = b2 / per_e;
    const int b = b2 - e * per_e;
    const float* src; u16* dst;
    size_t sstride, dstride;
    int r0, c0;
    if (b < ntile1) {
        int tr = b / tiles_h, tc = b % tiles_h;
        r0 = tr * 64; c0 = tc * 64;
        src = w1 + (size_t)e * D_IN * H_DIM + (size_t)chunk * HC;
        sstride = H_DIM;
        dst = w1t + (size_t)e * HC * D_IN;
        dstride = D_IN;
    } else {
        int tb = b - ntile1;
        int tr = tb / 16, tc = tb % 16;
        r0 = tr * 64; c0 = tc * 64;
        src = w2 + ((size_t)e * H_DIM + (size_t)chunk * HC) * DO_DIM;
        sstride = DO_DIM;
        dst = w2t + (size_t)e * DO_DIM * HC;
        dstride = HC;
    }
#pragma unroll
    for (int i = 0; i < 4; ++i) {
        int flat = i * 1024 + tid * 4;
        int rr = flat >> 6, cc = flat & 63;
        float4 v = *(const float4*)(src + (size_t)(r0 + rr) * sstride + c0 + cc);
        ushort4 h4;
        h4.x = f2bf(v.x); h4.y = f2bf(v.y); h4.z = f2bf(v.z); h4.w = f2bf(v.w);
        *(ushort4*)&tile[rr][cc] = h4;
    }
    __syncthreads();
#pragma unroll
    for (int i = 0; i < 4; ++i) {
        int flat = i * 1024 + tid * 4;
        int rr = flat >> 6, cc = flat & 63;
        ushort4 o;
        o.x = tile[cc + 0][rr]; o.y = tile[cc + 1][rr];
        o.z = tile[cc + 2][rr]; o.w = tile[cc + 3][rr];
        *(ushort4*)(dst + (size_t)(c0 + rr) * dstride + r0 + cc) = o;
    }
}

__global__ void zero_counts_kernel(int* c) { c[threadIdx.x] = 0; }   // 256 ints (padded)

// scan padded gcounts -> compact counts, base[], usage, dense 128-row block table
__global__ void scan_kernel(const int* __restrict__ gcounts, int* __restrict__ counts,
                            int* __restrict__ base, float* __restrict__ usage_out,
                            int* __restrict__ rbt) {
    if (threadIdx.x == 0) {
        int acc = 0;
        for (int e = 0; e < 8; ++e) {
            int c = gcounts[e * 32];
            counts[e] = c;
            base[e] = acc;
            acc += c;
            usage_out[e] = (float)c;
        }
        int nrb = 0;
        for (int e = 0; e < 8; ++e) {
            int nb = (counts[e] + 127) >> 7;
            for (int rb = 0; rb < nb; ++rb) rbt[1 + nrb++] = (e << 16) | rb;
        }
        rbt[0] = nrb;   // <= 135
    }
}

// ---------------- gather: xg[slot][d] = bf16(x[tok][d]) ----------------
__global__ __launch_bounds__(256) void gather_kernel(
    const float* __restrict__ x, const int* __restrict__ slot_of_tok,
    const int* __restrict__ base, u16* __restrict__ xg)
{
    const int t = blockIdx.x;
    const int s = slot_of_tok[t * 2 + blockIdx.y];
    const int slot = base[s >> 13] + (s & 8191);
    const int d = threadIdx.x * 4;
    float4 v = *(const float4*)(x + ((size_t)t << 10) + d);
    ushort4 h;
    h.x = f2bf(v.x); h.y = f2bf(v.y); h.z = f2bf(v.z); h.w = f2bf(v.w);
    *(ushort4*)(xg + ((size_t)slot << 10) + d) = h;
}

// ====================== 128x256 BK=64 depth-3 pipelined MFMA GEMM cores ======================
// r11/r12/r14-verified schedule (204us, 674TF, MfmaUtil 29, 0 bank conflicts), UNCHANGED.
// r16: 1D grid + xcd_map so all column-blocks sharing an A-panel run on one XCD (the
// A-panel, ~1MB, then lives in that XCD's 4MB L2 instead of being re-fetched per XCD).

__device__ __forceinline__ void stage6s(const char* const gA[2], const char* const gB[4],
                                        char* slab, int koff, int tid) {
    char* l = slab + __builtin_amdgcn_readfirstlane((tid >> 6) << 10);
#pragma unroll
    for (int i = 0; i < 2; ++i) gload16(gA[i] + koff, l + i * 8192);
#pragma unroll
    for (int i = 0; i < 4; ++i) gload16(gB[i] + koff, l + 16384 + i * 8192);
}

#define MFMA_BLOCK(S) do { \
    s16x8 la0[4], lb0[4], la1[4], lb1[4]; \
    _Pragma("unroll") \
    for (int m = 0; m < 4; ++m) la0[m] = *(const s16x8*)((S) + aoff0 + m * 2048); \
    _Pragma("unroll") \
    for (int n = 0; n < 4; ++n) lb0[n] = *(const s16x8*)((S) + boff0 + n * 2048); \
    _Pragma("unroll") \
    for (int m = 0; m < 4; ++m) la1[m] = *(const s16x8*)((S) + aoff1 + m * 2048); \
    _Pragma("unroll") \
    for (int n = 0; n < 4; ++n) lb1[n] = *(const s16x8*)((S) + boff1 + n * 2048); \
    __builtin_amdgcn_s_setprio(1); \
    _Pragma("unroll") \
    for (int m = 0; m < 4; ++m) \
        _Pragma("unroll") \
        for (int n = 0; n < 4; ++n) acc[m][n] = mfma16(la0[m], lb0[n], acc[m][n]); \
    _Pragma("unroll") \
    for (int m = 0; m < 4; ++m) \
        _Pragma("unroll") \
        for (int n = 0; n < 4; ++n) acc[m][n] = mfma16(la1[m], lb1[n], acc[m][n]); \
    __builtin_amdgcn_s_setprio(0); } while(0)

#define GEMM_CORE(NTV) \
    const int arow = (wm << 6) + (lane & 15); \
    const int brow = (wn << 6) + (lane & 15); \
    const int ko = (lane >> 4) << 4; \
    const int aoff0 = arow * 128 + (ko ^ ((arow & 7) << 4)); \
    const int aoff1 = arow * 128 + ((64 + ko) ^ ((arow & 7) << 4)); \
    const int boff0 = 16384 + brow * 128 + (ko ^ ((brow & 7) << 4)); \
    const int boff1 = 16384 + brow * 128 + ((64 + ko) ^ ((brow & 7) << 4)); \
    f32x4 acc[4][4]; \
    _Pragma("unroll") \
    for (int m = 0; m < 4; ++m) \
        _Pragma("unroll") \
        for (int n = 0; n < 4; ++n) acc[m][n] = f32x4{0.f, 0.f, 0.f, 0.f}; \
    stage6s(gA, gB, sm, 0, tid); \
    stage6s(gA, gB, sm + 49152, 128, tid); \
    int cs = 0; \
    _Pragma("unroll 1") \
    for (int t = 0; t < (NTV); ++t) { \
        if (t + 1 < (NTV)) asm volatile("s_waitcnt vmcnt(6)" ::: "memory"); \
        else               asm volatile("s_waitcnt vmcnt(0)" ::: "memory"); \
        __builtin_amdgcn_sched_barrier(0); \
        __builtin_amdgcn_s_barrier(); \
        __builtin_amdgcn_sched_barrier(0); \
        if (t + 2 < (NTV)) { \
            int ss = cs + 2; if (ss >= 3) ss -= 3; \
            stage6s(gA, gB, sm + ss * 49152, (t + 2) * 128, tid); \
        } \
        const char* S_ = sm + cs * 49152; \
        MFMA_BLOCK(S_); \
        cs = cs + 1; if (cs == 3) cs = 0; \
    }

// ---------------- GEMM1: hbuf[slot][hh] = relu(xg[slot] @ w1t[e] + b1[e]), bf16 out ----------------
__global__ __launch_bounds__(512) void gemm1_kernel(
    const u16* __restrict__ xg, const u16* __restrict__ w1t,
    const float* __restrict__ b1, u16* __restrict__ hbuf,
    const int* __restrict__ counts, const int* __restrict__ base,
    const int* __restrict__ rbt, int chunk, int HC, int ncol)
{
    int bx, by;
    xcd_map(blockIdx.x, ncol, &bx, &by);
    const int nrb = rbt[0];
    if (by >= nrb) return;
    const int ent = rbt[1 + by];
    const int e = ent >> 16;
    const int row0 = (ent & 0xffff) << 7;        // 128-row blocks
    const int n_e = counts[e];
    const int sbase = base[e];
    const int col0 = bx << 8;                    // 256-col blocks
    const int tid = threadIdx.x;
    const int lane = tid & 63;
    const int wv = tid >> 6;
    const int wm = wv >> 2;                      // 0..1
    const int wn = wv & 3;                       // 0..3

    __shared__ char sm[147456];                  // 3 x 48KB (A 16KB | B 32KB)

    const int scb_ = ((tid & 7) << 4) ^ (((tid >> 3) & 7) << 4);
    const char* gA[2]; const char* gB[4];
#pragma unroll
    for (int i = 0; i < 2; ++i) {
        int slot = sbase + row0 + i * 64 + (tid >> 3);
        slot = slot < 16383 ? slot : 16383;      // clamp tail (guarded at C-write)
        gA[i] = (const char*)xg + ((size_t)slot << 11) + scb_;
    }
#pragma unroll
    for (int i = 0; i < 4; ++i) {
        int hrow = col0 + i * 64 + (tid >> 3);   // < HC
        gB[i] = (const char*)w1t + (((size_t)e * HC + hrow) << 11) + scb_;
    }

    GEMM_CORE(16)    // NT = D_IN/64

    // epilogue: bias + relu + cvt, guarded rows
    const int crow = (wm << 6) + ((lane >> 4) << 2);
    const int ccol = (wn << 6) + (lane & 15);
    float bias_n[4];
#pragma unroll
    for (int n = 0; n < 4; ++n)
        bias_n[n] = b1[(e << 12) + chunk * HC + col0 + ccol + n * 16];
#pragma unroll
    for (int m = 0; m < 4; ++m) {
#pragma unroll
        for (int j = 0; j < 4; ++j) {
            int r = row0 + crow + m * 16 + j;
            if (r < n_e) {
                u16* dst = hbuf + (size_t)(sbase + r) * HC + col0;
#pragma unroll
                for (int n = 0; n < 4; ++n) {
                    float v = acc[m][n][j] + bias_n[n];
                    v = v > 0.f ? v : 0.f;
                    dst[ccol + n * 16] = f2bf(v);
                }
            }
        }
    }
}

// ---------------- GEMM2: eo[slot][o] (+)= hbuf[slot] @ w2t[e] (+ b2 on chunk 0), f32 out ----------------
__global__ __launch_bounds__(512) void gemm2_kernel(
    const u16* __restrict__ hbuf, const u16* __restrict__ w2t,
    const float* __restrict__ b2, float* __restrict__ eo,
    const int* __restrict__ counts, const int* __restrict__ base,
    const int* __restrict__ rbt, int chunk, int HC)
{
    int bx, by;
    xcd_map(blockIdx.x, 4, &bx, &by);
    const int nrb = rbt[0];
    if (by >= nrb) return;
    const int ent = rbt[1 + by];
    const int e = ent >> 16;
    const int row0 = (ent & 0xffff) << 7;
    const int n_e = counts[e];
    const int sbase = base[e];
    const int col0 = bx << 8;
    const int tid = threadIdx.x;
    const int lane = tid & 63;
    const int wv = tid >> 6;
    const int wm = wv >> 2;
    const int wn = wv & 3;

    __shared__ char sm[147456];

    const int scb_ = ((tid & 7) << 4) ^ (((tid >> 3) & 7) << 4);
    const char* gA[2]; const char* gB[4];
#pragma unroll
    for (int i = 0; i < 2; ++i) {
        int slot = sbase + row0 + i * 64 + (tid >> 3);
        slot = slot < 16383 ? slot : 16383;
        gA[i] = (const char*)hbuf + (((size_t)slot * HC) << 1) + scb_;
    }
#pragma unroll
    for (int i = 0; i < 4; ++i) {
        int orow = col0 + i * 64 + (tid >> 3);   // < 1024
        gB[i] = (const char*)w2t + ((((size_t)(e << 10) + orow) * HC) << 1) + scb_;
    }

    const int NT = HC >> 6;
    GEMM_CORE(NT)

    const int crow = (wm << 6) + ((lane >> 4) << 2);
    const int ccol = (wn << 6) + (lane & 15);
    float bias_n[4];
#pragma unroll
    for (int n = 0; n < 4; ++n)
        bias_n[n] = (chunk == 0) ? b2[(e << 10) + col0 + ccol + n * 16] : 0.f;
#pragma unroll
    for (int m = 0; m < 4; ++m) {
#pragma unroll
        for (int j = 0; j < 4; ++j) {
            int r = row0 + crow + m * 16 + j;
            if (r < n_e) {
                float* dst = eo + ((size_t)(sbase + r) << 10) + col0;
#pragma unroll
                for (int n = 0; n < 4; ++n) {
                    int c = ccol + n * 16;
                    float v = acc[m][n][j] + bias_n[n];
                    if (chunk) v += dst[c];
                    dst[c] = v;
                }
            }
        }
    }
}

// ---------------- combine: out[t] = w0*eo[s0] + w1*eo[s1] (deterministic) ----------------
__global__ __launch_bounds__(256) void combine_kernel(
    const float* __restrict__ eo, const float* __restrict__ weights,
    const int* __restrict__ slot_of_tok, const int* __restrict__ base,
    float* __restrict__ out)
{
    const int t = blockIdx.x;
    const int tid = threadIdx.x;
    int s0 = slot_of_tok[t * 2], s1 = slot_of_tok[t * 2 + 1];
    int e0 = s0 >> 13, e1 = s1 >> 13;
    int c0 = base[e0] + (s0 & 8191);
    int c1 = base[e1] + (s1 & 8191);
    float w0 = weights[t * 8 + e0];
    float w1 = weights[t * 8 + e1];
    int c = tid * 4;
    f32x4 a = *(const f32x4*)(eo + ((size_t)c0 << 10) + c);
    f32x4 b = *(const f32x4*)(eo + ((size_t)c1 << 10) + c);
    f32x4 r;
    r[0] = w0 * a[0] + w1 * b[0];
    r[1] = w0 * a[1] + w1 * b[1];
    r[2] = w0 * a[2] + w1 * b[2];
    r[3] = w0 * a[3] + w1 * b[3];
    *(f32x4*)(out + ((size_t)t << 10) + c) = r;
}

extern "C" void kernel_launch(void* const* d_in, const int* in_sizes, int n_in,
                              void* d_out, int out_size, void* d_ws, size_t ws_size,
                              hipStream_t stream)
{
    const float* x      = (const float*)d_in[0];
    const float* gate_w = (const float*)d_in[1];
    const float* gate_b = (const float*)d_in[2];
    const float* w1     = (const float*)d_in[3];
    const float* b1     = (const float*)d_in[4];
    const float* w2     = (const float*)d_in[5];
    const float* b2     = (const float*)d_in[6];

    float* out         = (float*)d_out;                      // [8192,1024]
    float* weights_out = out + (size_t)T_TOK * DO_DIM;       // [8192,8]
    float* usage_out   = weights_out + (size_t)T_TOK * 8;    // [8]
    float* topi_out    = usage_out + 8;                      // [8192,2]

    char* p = (char*)d_ws;
    int* gcounts = (int*)p;      p += 1024;                  // padded: e*32, 128B apart
    int* counts = (int*)p;       p += 256;
    int* base   = (int*)p;       p += 256;
    int* rbt    = (int*)p;       p += 1024;                  // 1 + <=135 entries
    int* tok_list = (int*)p;     p += (size_t)8 * 8192 * 4;
    int* slot_of_tok = (int*)p;  p += (size_t)8192 * 2 * 4;
    const size_t fixed = (size_t)(p - (char*)d_ws);

    // xg 32MiB + eo 64MiB fixed; per-HC: w1t+w2t+hbuf = 65536*HC bytes
    const size_t xg_bytes = (size_t)16384 * 1024 * 2;
    const size_t eo_bytes = (size_t)16384 * 1024 * 4;
    int HC;
    if      (ws_size >= fixed + xg_bytes + eo_bytes + (size_t)65536 * 4096) HC = 4096;
    else if (ws_size >= fixed + xg_bytes + eo_bytes + (size_t)65536 * 2048) HC = 2048;
    else if (ws_size >= fixed + xg_bytes + eo_bytes + (size_t)65536 * 1024) HC = 1024;
    else                                                                    HC = 512;

    u16* xg   = (u16*)p; p += xg_bytes;
    u16* w1t  = (u16*)p; p += (size_t)8 * HC * 1024 * 2;
    u16* w2t  = (u16*)p; p += (size_t)8 * 1024 * HC * 2;
    u16* hbuf = (u16*)p; p += (size_t)16384 * HC * 2;
    float* eo = (float*)p;

    const int tiles_h = HC / 64;
    const int per_e = 32 * tiles_h;
    const int trans_blocks = 8 * per_e;

    zero_counts_kernel<<<1, 256, 0, stream>>>(gcounts);
    gate_transpose_kernel<<<512 + trans_blocks, 256, 0, stream>>>(
        x, gate_w, gate_b, weights_out, topi_out, gcounts, tok_list, slot_of_tok,
        w1, w2, w1t, w2t, 0, HC, 512);
    scan_kernel<<<1, 64, 0, stream>>>(gcounts, counts, base, usage_out, rbt);
    gather_kernel<<<dim3(T_TOK, 2), 256, 0, stream>>>(x, slot_of_tok, base, xg);

    const int NC = H_DIM / HC;
    for (int c = 0; c < NC; ++c) {
        if (c > 0)
            gate_transpose_kernel<<<trans_blocks, 256, 0, stream>>>(
                x, gate_w, gate_b, weights_out, topi_out, gcounts, tok_list, slot_of_tok,
                w1, w2, w1t, w2t, c, HC, 0);
        const int ncol1 = HC / 256;
        gemm1_kernel<<<ncol1 * NRBP, 512, 0, stream>>>(xg, w1t, b1, hbuf,
                                                       counts, base, rbt, c, HC, ncol1);
        gemm2_kernel<<<4 * NRBP, 512, 0, stream>>>(hbuf, w2t, b2, eo,
                                                   counts, base, rbt, c, HC);
    }
    combine_kernel<<<T_TOK, 256, 0, stream>>>(eo, weights_out, slot_of_tok, base, out);
}